// Round 6
// baseline (534.595 us; speedup 1.0000x reference)
//
#include <hip/hip_runtime.h>
#include <hip/hip_bf16.h>
#include <math.h>

typedef __attribute__((ext_vector_type(8))) short short8;
typedef __attribute__((ext_vector_type(4))) float f32x4;

namespace {
// ---- LDS arena word layout ----
constexpr int XP = 61;          // padded x row stride (words)
constexpr int EB0 = 3660;       // ebar [60][20]
constexpr int Y0 = 4860;        // y [5][14]
constexpr int ZSLOT = 4930;     // zero word
constexpr int ARENA_W = 4931;

// ---- ws byte offsets ----
constexpr int NTAB_PP = 222 * 4 * 64 * 8;   // u16 entries
constexpr int NTAB_PV = 53 * 3 * 64 * 8;
constexpr int NTAB_O  = 4 * 3 * 64 * 8;
constexpr int TABPP_B = 0;
constexpr int TABPV_B = TABPP_B + NTAB_PP * 2;   // 909312
constexpr int TABO_B  = TABPV_B + NTAB_PV * 2;   // 1072128
constexpr int WPP1_B  = TABO_B + NTAB_O * 2;     // 1084416
constexpr int WPP2_B  = WPP1_B + 16 * 64 * 16;
constexpr int WPV1_B  = WPP2_B + 4 * 64 * 16;
constexpr int WPV2_B  = WPV1_B + 12 * 64 * 16;
constexpr int WO1_B   = WPV2_B + 4 * 64 * 16;
constexpr int WO2_B   = WO1_B + 12 * 64 * 16;
constexpr int BIAS_B  = WO2_B + 4 * 64 * 16;     // 288 f32
}

__device__ __forceinline__ short f2bfs(float f) {
  __hip_bfloat16 h = __float2bfloat16(f);
  short s;
  __builtin_memcpy(&s, &h, 2);
  return s;
}

// ---------------- init: gather tables (u16 BYTE offsets into arena) ----------------
__global__ __launch_bounds__(256) void build_tables(char* wsb) {
  int t = blockIdx.x * 256 + threadIdx.x;
  unsigned short* tpp = (unsigned short*)(wsb + TABPP_B);
  unsigned short* tpv = (unsigned short*)(wsb + TABPV_B);
  unsigned short* tou = (unsigned short*)(wsb + TABO_B);
  if (t < NTAB_PP) {
    int j = t & 7, l = (t >> 3) & 63, blk = t >> 9;
    int ks = blk & 3, mt = blk >> 2;
    int rr = mt * 16 + (l & 15), k = ks * 32 + (l >> 4) * 8 + j;
    unsigned off = ZSLOT;
    if (rr < 3540 && k < 120) {
      unsigned p = (unsigned)rr * 120u + (unsigned)k;
      unsigned f = p / 3540u, e = p - f * 3540u;
      unsigned i = e / 59u, jj = e - i * 59u;
      unsigned col = (f < 60u) ? i : ((jj < i) ? jj : jj + 1u);
      unsigned ft = (f < 60u) ? f : f - 60u;
      off = ft * (unsigned)XP + col;
    }
    tpp[t] = (unsigned short)(off * 4u);
    return;
  }
  t -= NTAB_PP;
  if (t < NTAB_PV) {
    int j = t & 7, l = (t >> 3) & 63, blk = t >> 9;
    int ks = blk % 3, mt = blk / 3;
    int tt = mt * 16 + (l & 15), k = ks * 32 + (l >> 4) * 8 + j;
    unsigned off = ZSLOT;
    if (tt < 840 && k < 65) {
      int i = tt / 14, v = tt - i * 14;
      off = (k < 60) ? (unsigned)(k * XP + i) : (unsigned)(Y0 + (k - 60) * 14 + v);
    }
    tpv[t] = (unsigned short)(off * 4u);
    return;
  }
  t -= NTAB_PV;
  if (t < NTAB_O) {
    int j = t & 7, l = (t >> 3) & 63, blk = t >> 9;
    int ks = blk % 3, mt = blk / 3;
    int r = mt * 16 + (l & 15), k = ks * 32 + (l >> 4) * 8 + j;
    unsigned off = ZSLOT;
    if (r < 60 && k < 80)
      off = (k < 60) ? (unsigned)(r * XP + k) : (unsigned)(EB0 + r * 20 + (k - 60));
    tou[t] = (unsigned short)(off * 4u);
  }
}

// ---------------- init: weight fragments (bf16, B-layout) + padded biases ----------------
__global__ __launch_bounds__(256) void build_wfrag(char* wsb,
    const float* W1pp, const float* W2pp, const float* W1pv, const float* W2pv,
    const float* W1o, const float* W2o,
    const float* b1pp, const float* b2pp, const float* b1pv, const float* b2pv,
    const float* b1o, const float* b2o) {
  int t = blockIdx.x * 256 + threadIdx.x;
  if (t < 13312) {
    const float* W; int Kt, Nt, NTt; unsigned* dst; int local;
    if (t < 4096)       { W = W1pp; Kt = 120; Nt = 60; NTt = 4; dst = (unsigned*)(wsb + WPP1_B); local = t; }
    else if (t < 5120)  { W = W2pp; Kt = 60;  Nt = 20; NTt = 2; dst = (unsigned*)(wsb + WPP2_B); local = t - 4096; }
    else if (t < 8192)  { W = W1pv; Kt = 65;  Nt = 60; NTt = 4; dst = (unsigned*)(wsb + WPV1_B); local = t - 5120; }
    else if (t < 9216)  { W = W2pv; Kt = 60;  Nt = 20; NTt = 2; dst = (unsigned*)(wsb + WPV2_B); local = t - 8192; }
    else if (t < 12288) { W = W1o;  Kt = 80;  Nt = 60; NTt = 4; dst = (unsigned*)(wsb + WO1_B);  local = t - 9216; }
    else                { W = W2o;  Kt = 60;  Nt = 24; NTt = 2; dst = (unsigned*)(wsb + WO2_B);  local = t - 12288; }
    int d = local & 3, l = (local >> 2) & 63, rest = local >> 8;
    int nt = rest % NTt, ks = rest / NTt;
    int k = ks * 32 + (l >> 4) * 8 + 2 * d, n = nt * 16 + (l & 15);
    float v0 = (k < Kt && n < Nt) ? W[k * Nt + n] : 0.f;
    float v1 = (k + 1 < Kt && n < Nt) ? W[(k + 1) * Nt + n] : 0.f;
    unsigned u0 = (unsigned short)f2bfs(v0);
    unsigned u1 = (unsigned short)f2bfs(v1);
    dst[local] = u0 | (u1 << 16);
    return;
  }
  t -= 13312;
  if (t < 288) {
    float* bd = (float*)(wsb + BIAS_B);
    float v = 0.f;
    if (t < 64)       { if (t < 60) v = b1pp[t]; }
    else if (t < 96)  { int n = t - 64;  if (n < 20) v = b2pp[n]; }
    else if (t < 160) { int n = t - 96;  if (n < 60) v = b1pv[n]; }
    else if (t < 192) { int n = t - 160; if (n < 20) v = b2pv[n]; }
    else if (t < 256) { int n = t - 192; if (n < 60) v = b1o[n]; }
    else              { int n = t - 256; if (n < 24) v = b2o[n]; }
    bd[t] = v;
  }
}

__device__ __forceinline__ short8 gather8(const char* xb, uint4 tw) {
  float g0 = *(const float*)(xb + (tw.x & 0xffffu));
  float g1 = *(const float*)(xb + (tw.x >> 16));
  float g2 = *(const float*)(xb + (tw.y & 0xffffu));
  float g3 = *(const float*)(xb + (tw.y >> 16));
  float g4 = *(const float*)(xb + (tw.z & 0xffffu));
  float g5 = *(const float*)(xb + (tw.z >> 16));
  float g6 = *(const float*)(xb + (tw.w & 0xffffu));
  float g7 = *(const float*)(xb + (tw.w >> 16));
  short8 af;
  af[0] = f2bfs(g0); af[1] = f2bfs(g1); af[2] = f2bfs(g2); af[3] = f2bfs(g3);
  af[4] = f2bfs(g4); af[5] = f2bfs(g5); af[6] = f2bfs(g6); af[7] = f2bfs(g7);
  return af;
}

// ---- dual-tile MLP: stage1 MFMA (shared weight loads) -> relu -> H LDS -> stage2 MFMA ----
// A-frag: lane holds A[m=l&15][k=(l>>4)*8+j]; C/D: col=l&15, row=(l>>4)*4+reg.
template <int NKS, bool DUAL>
__device__ __forceinline__ void mlp_tiles(
    int mtA, int mtB, int lane,
    const uint4* __restrict__ tab,
    const short8* __restrict__ wf1, const short8* __restrict__ wf2,
    const float (&b1v)[4], const float (&b2v)[2],
    const float* arena, short (*bufA)[72], short (*bufB)[72],
    f32x4 (&a2A)[2], f32x4 (&a2B)[2])
{
  const int cl = lane & 15, qq = lane >> 4;
  const char* xb = (const char*)arena;

  f32x4 accA[4], accB[4];
#pragma unroll
  for (int nt = 0; nt < 4; ++nt) {
    float bv = b1v[nt];
    accA[nt] = (f32x4){bv, bv, bv, bv};
    if constexpr (DUAL) accB[nt] = (f32x4){bv, bv, bv, bv};
  }

#pragma unroll
  for (int ks = 0; ks < NKS; ++ks) {
    uint4 twA = tab[(mtA * NKS + ks) * 64 + lane];
    uint4 twB;
    if constexpr (DUAL) twB = tab[(mtB * NKS + ks) * 64 + lane];
    short8 afA = gather8(xb, twA);
    short8 afB;
    if constexpr (DUAL) afB = gather8(xb, twB);
#pragma unroll
    for (int nt = 0; nt < 4; ++nt) {
      short8 wf = wf1[(ks * 4 + nt) * 64 + lane];
      accA[nt] = __builtin_amdgcn_mfma_f32_16x16x32_bf16(afA, wf, accA[nt], 0, 0, 0);
      if constexpr (DUAL)
        accB[nt] = __builtin_amdgcn_mfma_f32_16x16x32_bf16(afB, wf, accB[nt], 0, 0, 0);
    }
  }

  // relu -> per-wave H tiles (bf16, rows padded to 72 shorts = 144B, 16B-aligned)
#pragma unroll
  for (int nt = 0; nt < 4; ++nt)
#pragma unroll
    for (int r = 0; r < 4; ++r) {
      bufA[qq * 4 + r][nt * 16 + cl] = f2bfs(fmaxf(accA[nt][r], 0.f));
      if constexpr (DUAL)
        bufB[qq * 4 + r][nt * 16 + cl] = f2bfs(fmaxf(accB[nt][r], 0.f));
    }

#pragma unroll
  for (int nt = 0; nt < 2; ++nt) {
    float bv = b2v[nt];
    a2A[nt] = (f32x4){bv, bv, bv, bv};
    if constexpr (DUAL) a2B[nt] = (f32x4){bv, bv, bv, bv};
  }
#pragma unroll
  for (int k2 = 0; k2 < 2; ++k2) {
    short8 hA = *(const short8*)&bufA[cl][k2 * 32 + qq * 8];
    short8 hB;
    if constexpr (DUAL) hB = *(const short8*)&bufB[cl][k2 * 32 + qq * 8];
#pragma unroll
    for (int nt = 0; nt < 2; ++nt) {
      short8 wf = wf2[(k2 * 2 + nt) * 64 + lane];
      a2A[nt] = __builtin_amdgcn_mfma_f32_16x16x32_bf16(hA, wf, a2A[nt], 0, 0, 0);
      if constexpr (DUAL)
        a2B[nt] = __builtin_amdgcn_mfma_f32_16x16x32_bf16(hB, wf, a2B[nt], 0, 0, 0);
    }
  }
}

template <int DIV, int LIM>
__device__ __forceinline__ void scatter_e(const f32x4 (&a2)[2], int rb, float* eb, int cl) {
  int riA = rb / DIV, riB = (rb + 3) / DIV;
#pragma unroll
  for (int nt = 0; nt < 2; ++nt) {
    int col = nt * 16 + cl;
    if (col < 20) {
      if (riA == riB && rb + 3 < LIM) {
        atomicAdd(&eb[riA * 20 + col], a2[nt][0] + a2[nt][1] + a2[nt][2] + a2[nt][3]);
      } else {
#pragma unroll
        for (int r = 0; r < 4; ++r) {
          int rr = rb + r;
          if (rr < LIM) atomicAdd(&eb[(rr / DIV) * 20 + col], a2[nt][r]);
        }
      }
    }
  }
}

// ---------------- fused kernel: one block per batch element ----------------
__global__ __launch_bounds__(256, 4) void fused_kernel(
    const float* __restrict__ x, const float* __restrict__ y,
    const float* __restrict__ Wc, const float* __restrict__ Bc,
    const char* __restrict__ wsb, float* __restrict__ out) {
  __shared__ float arena[ARENA_W];
  __shared__ short hlds[4][2][16][72];   // per-wave double-buffered H tiles
  __shared__ float osum[24];

  const int b = blockIdx.x;
  const int tid = threadIdx.x;
  const int w = tid >> 6;
  const int lane = tid & 63;
  const int cl = lane & 15, q4 = (lane >> 4) * 4;

  for (int k = tid; k < 3600; k += 256) {
    int r = k / 60, c = k - r * 60;
    arena[r * XP + c] = x[(size_t)b * 3600 + k];
  }
  if (tid < 70) arena[Y0 + tid] = y[(size_t)b * 70 + tid];
  for (int k = tid; k < 1200; k += 256) arena[EB0 + k] = 0.f;
  if (tid == 0) arena[ZSLOT] = 0.f;
  if (tid < 24) osum[tid] = 0.f;
  __syncthreads();

  const float* biasf = (const float*)(wsb + BIAS_B);

  // ================= particle-particle =================
  {
    const short8* wf1 = (const short8*)(wsb + WPP1_B);
    const short8* wf2 = (const short8*)(wsb + WPP2_B);
    const uint4* tab = (const uint4*)(wsb + TABPP_B);
    float b1v[4], b2v[2];
#pragma unroll
    for (int nt = 0; nt < 4; ++nt) b1v[nt] = biasf[0 + nt * 16 + cl];
#pragma unroll
    for (int nt = 0; nt < 2; ++nt) b2v[nt] = biasf[64 + nt * 16 + cl];

    int mt = w;
    for (; mt + 4 < 222; mt += 8) {
      f32x4 a2A[2], a2B[2];
      mlp_tiles<4, true>(mt, mt + 4, lane, tab, wf1, wf2, b1v, b2v, arena,
                         hlds[w][0], hlds[w][1], a2A, a2B);
      scatter_e<59, 3540>(a2A, mt * 16 + q4, &arena[EB0], cl);
      scatter_e<59, 3540>(a2B, (mt + 4) * 16 + q4, &arena[EB0], cl);
    }
    if (mt < 222) {
      f32x4 a2A[2], a2B[2];
      mlp_tiles<4, false>(mt, mt, lane, tab, wf1, wf2, b1v, b2v, arena,
                          hlds[w][0], hlds[w][1], a2A, a2B);
      scatter_e<59, 3540>(a2A, mt * 16 + q4, &arena[EB0], cl);
    }
  }

  // ================= particle-vertex =================
  {
    const short8* wf1 = (const short8*)(wsb + WPV1_B);
    const short8* wf2 = (const short8*)(wsb + WPV2_B);
    const uint4* tab = (const uint4*)(wsb + TABPV_B);
    float b1v[4], b2v[2];
#pragma unroll
    for (int nt = 0; nt < 4; ++nt) b1v[nt] = biasf[96 + nt * 16 + cl];
#pragma unroll
    for (int nt = 0; nt < 2; ++nt) b2v[nt] = biasf[160 + nt * 16 + cl];

    int mt = w;
    for (; mt + 4 < 53; mt += 8) {
      f32x4 a2A[2], a2B[2];
      mlp_tiles<3, true>(mt, mt + 4, lane, tab, wf1, wf2, b1v, b2v, arena,
                         hlds[w][0], hlds[w][1], a2A, a2B);
      scatter_e<14, 840>(a2A, mt * 16 + q4, &arena[EB0], cl);
      scatter_e<14, 840>(a2B, (mt + 4) * 16 + q4, &arena[EB0], cl);
    }
    if (mt < 53) {
      f32x4 a2A[2], a2B[2];
      mlp_tiles<3, false>(mt, mt, lane, tab, wf1, wf2, b1v, b2v, arena,
                          hlds[w][0], hlds[w][1], a2A, a2B);
      scatter_e<14, 840>(a2A, mt * 16 + q4, &arena[EB0], cl);
    }
  }

  __syncthreads();  // ebar complete

  // ================= output MLP (4 tiles, one per wave) =================
  {
    const short8* wf1 = (const short8*)(wsb + WO1_B);
    const short8* wf2 = (const short8*)(wsb + WO2_B);
    const uint4* tab = (const uint4*)(wsb + TABO_B);
    float b1v[4], b2v[2];
#pragma unroll
    for (int nt = 0; nt < 4; ++nt) b1v[nt] = biasf[192 + nt * 16 + cl];
#pragma unroll
    for (int nt = 0; nt < 2; ++nt) b2v[nt] = biasf[256 + nt * 16 + cl];

    f32x4 a2A[2], a2B[2];
    mlp_tiles<3, false>(w, w, lane, tab, wf1, wf2, b1v, b2v, arena,
                        hlds[w][0], hlds[w][1], a2A, a2B);
    int rb = w * 16 + q4;
#pragma unroll
    for (int nt = 0; nt < 2; ++nt) {
      int col = nt * 16 + cl;
      if (col < 24) {
        if (rb + 3 < 60) {
          atomicAdd(&osum[col], a2A[nt][0] + a2A[nt][1] + a2A[nt][2] + a2A[nt][3]);
        } else {
#pragma unroll
          for (int r = 0; r < 4; ++r)
            if (rb + r < 60) atomicAdd(&osum[col], a2A[nt][r]);
        }
      }
    }
  }

  __syncthreads();
  if (tid == 0) {
    float sd = Bc[0];
#pragma unroll
    for (int o = 0; o < 24; ++o) sd = fmaf(osum[o], Wc[o], sd);
    out[b] = 1.f / (1.f + expf(-sd));
  }
}

extern "C" void kernel_launch(void* const* d_in, const int* in_sizes, int n_in,
                              void* d_out, int out_size, void* d_ws, size_t ws_size,
                              hipStream_t stream) {
  const float* x     = (const float*)d_in[0];
  const float* y     = (const float*)d_in[1];
  const float* W1_pp = (const float*)d_in[2];
  const float* b1_pp = (const float*)d_in[3];
  const float* W2_pp = (const float*)d_in[4];
  const float* b2_pp = (const float*)d_in[5];
  const float* W1_pv = (const float*)d_in[6];
  const float* b1_pv = (const float*)d_in[7];
  const float* W2_pv = (const float*)d_in[8];
  const float* b2_pv = (const float*)d_in[9];
  const float* W1_o  = (const float*)d_in[10];
  const float* b1_o  = (const float*)d_in[11];
  const float* W2_o  = (const float*)d_in[12];
  const float* b2_o  = (const float*)d_in[13];
  const float* Wc    = (const float*)d_in[14];
  const float* bc    = (const float*)d_in[15];
  float* out = (float*)d_out;
  char* wsb = (char*)d_ws;

  const int Bb = in_sizes[0] / 3600;  // 1024
  const int tab_total = NTAB_PP + NTAB_PV + NTAB_O;

  build_tables<<<(tab_total + 255) / 256, 256, 0, stream>>>(wsb);
  build_wfrag<<<(13600 + 255) / 256, 256, 0, stream>>>(wsb,
      W1_pp, W2_pp, W1_pv, W2_pv, W1_o, W2_o,
      b1_pp, b2_pp, b1_pv, b2_pv, b1_o, b2_o);
  fused_kernel<<<Bb, 256, 0, stream>>>(x, y, Wc, bc, wsb, out);
}

// Round 7
// 336.836 us; speedup vs baseline: 1.5871x; 1.5871x over previous
//
#include <hip/hip_runtime.h>
#include <hip/hip_bf16.h>
#include <math.h>

typedef __attribute__((ext_vector_type(8))) short short8;
typedef __attribute__((ext_vector_type(4))) float f32x4;

namespace {
// ---- LDS arena word layout ----
constexpr int XP = 61;          // padded x row stride (words)
constexpr int EB0 = 3660;       // ebar [60][20]
constexpr int Y0 = 4860;        // y [5][14]
constexpr int ZSLOT = 4930;     // zero word
constexpr int ARENA_W = 4931;

// ---- ws byte offsets ----
constexpr int NTAB_PP = 222 * 4 * 64 * 8;   // u16 entries
constexpr int NTAB_PV = 53 * 3 * 64 * 8;
constexpr int NTAB_O  = 4 * 3 * 64 * 8;
constexpr int TABPP_B = 0;
constexpr int TABPV_B = TABPP_B + NTAB_PP * 2;   // 909312
constexpr int TABO_B  = TABPV_B + NTAB_PV * 2;   // 1072128
constexpr int WPP1_B  = TABO_B + NTAB_O * 2;     // 1084416 (16 frags, then 4 stage2 frags contiguous)
constexpr int WPP2_B  = WPP1_B + 16 * 64 * 16;
constexpr int WPV1_B  = WPP2_B + 4 * 64 * 16;
constexpr int WPV2_B  = WPV1_B + 12 * 64 * 16;
constexpr int WO1_B   = WPV2_B + 4 * 64 * 16;
constexpr int WO2_B   = WO1_B + 12 * 64 * 16;
constexpr int BIAS_B  = WO2_B + 4 * 64 * 16;     // 288 f32
}

__device__ __forceinline__ short f2bfs(float f) {
  __hip_bfloat16 h = __float2bfloat16(f);
  short s;
  __builtin_memcpy(&s, &h, 2);
  return s;
}

// ---------------- init: gather tables (u16 BYTE offsets into arena) ----------------
__global__ __launch_bounds__(256) void build_tables(char* wsb) {
  int t = blockIdx.x * 256 + threadIdx.x;
  unsigned short* tpp = (unsigned short*)(wsb + TABPP_B);
  unsigned short* tpv = (unsigned short*)(wsb + TABPV_B);
  unsigned short* tou = (unsigned short*)(wsb + TABO_B);
  if (t < NTAB_PP) {
    int j = t & 7, l = (t >> 3) & 63, blk = t >> 9;
    int ks = blk & 3, mt = blk >> 2;
    int rr = mt * 16 + (l & 15), k = ks * 32 + (l >> 4) * 8 + j;
    unsigned off = ZSLOT;
    if (rr < 3540 && k < 120) {
      unsigned p = (unsigned)rr * 120u + (unsigned)k;
      unsigned f = p / 3540u, e = p - f * 3540u;
      unsigned i = e / 59u, jj = e - i * 59u;
      unsigned col = (f < 60u) ? i : ((jj < i) ? jj : jj + 1u);
      unsigned ft = (f < 60u) ? f : f - 60u;
      off = ft * (unsigned)XP + col;
    }
    tpp[t] = (unsigned short)(off * 4u);
    return;
  }
  t -= NTAB_PP;
  if (t < NTAB_PV) {
    int j = t & 7, l = (t >> 3) & 63, blk = t >> 9;
    int ks = blk % 3, mt = blk / 3;
    int tt = mt * 16 + (l & 15), k = ks * 32 + (l >> 4) * 8 + j;
    unsigned off = ZSLOT;
    if (tt < 840 && k < 65) {
      int i = tt / 14, v = tt - i * 14;
      off = (k < 60) ? (unsigned)(k * XP + i) : (unsigned)(Y0 + (k - 60) * 14 + v);
    }
    tpv[t] = (unsigned short)(off * 4u);
    return;
  }
  t -= NTAB_PV;
  if (t < NTAB_O) {
    int j = t & 7, l = (t >> 3) & 63, blk = t >> 9;
    int ks = blk % 3, mt = blk / 3;
    int r = mt * 16 + (l & 15), k = ks * 32 + (l >> 4) * 8 + j;
    unsigned off = ZSLOT;
    if (r < 60 && k < 80)
      off = (k < 60) ? (unsigned)(r * XP + k) : (unsigned)(EB0 + r * 20 + (k - 60));
    tou[t] = (unsigned short)(off * 4u);
  }
}

// ---------------- init: weight fragments (bf16, B-layout) + padded biases ----------------
__global__ __launch_bounds__(256) void build_wfrag(char* wsb,
    const float* W1pp, const float* W2pp, const float* W1pv, const float* W2pv,
    const float* W1o, const float* W2o,
    const float* b1pp, const float* b2pp, const float* b1pv, const float* b2pv,
    const float* b1o, const float* b2o) {
  int t = blockIdx.x * 256 + threadIdx.x;
  if (t < 13312) {
    const float* W; int Kt, Nt, NTt; unsigned* dst; int local;
    if (t < 4096)       { W = W1pp; Kt = 120; Nt = 60; NTt = 4; dst = (unsigned*)(wsb + WPP1_B); local = t; }
    else if (t < 5120)  { W = W2pp; Kt = 60;  Nt = 20; NTt = 2; dst = (unsigned*)(wsb + WPP2_B); local = t - 4096; }
    else if (t < 8192)  { W = W1pv; Kt = 65;  Nt = 60; NTt = 4; dst = (unsigned*)(wsb + WPV1_B); local = t - 5120; }
    else if (t < 9216)  { W = W2pv; Kt = 60;  Nt = 20; NTt = 2; dst = (unsigned*)(wsb + WPV2_B); local = t - 8192; }
    else if (t < 12288) { W = W1o;  Kt = 80;  Nt = 60; NTt = 4; dst = (unsigned*)(wsb + WO1_B);  local = t - 9216; }
    else                { W = W2o;  Kt = 60;  Nt = 24; NTt = 2; dst = (unsigned*)(wsb + WO2_B);  local = t - 12288; }
    int d = local & 3, l = (local >> 2) & 63, rest = local >> 8;
    int nt = rest % NTt, ks = rest / NTt;
    int k = ks * 32 + (l >> 4) * 8 + 2 * d, n = nt * 16 + (l & 15);
    float v0 = (k < Kt && n < Nt) ? W[k * Nt + n] : 0.f;
    float v1 = (k + 1 < Kt && n < Nt) ? W[(k + 1) * Nt + n] : 0.f;
    unsigned u0 = (unsigned short)f2bfs(v0);
    unsigned u1 = (unsigned short)f2bfs(v1);
    dst[local] = u0 | (u1 << 16);
    return;
  }
  t -= 13312;
  if (t < 288) {
    float* bd = (float*)(wsb + BIAS_B);
    float v = 0.f;
    if (t < 64)       { if (t < 60) v = b1pp[t]; }
    else if (t < 96)  { int n = t - 64;  if (n < 20) v = b2pp[n]; }
    else if (t < 160) { int n = t - 96;  if (n < 60) v = b1pv[n]; }
    else if (t < 192) { int n = t - 160; if (n < 20) v = b2pv[n]; }
    else if (t < 256) { int n = t - 192; if (n < 60) v = b1o[n]; }
    else              { int n = t - 256; if (n < 24) v = b2o[n]; }
    bd[t] = v;
  }
}

__device__ __forceinline__ short8 gather8(const char* xb, uint4 tw) {
  float g0 = *(const float*)(xb + (tw.x & 0xffffu));
  float g1 = *(const float*)(xb + (tw.x >> 16));
  float g2 = *(const float*)(xb + (tw.y & 0xffffu));
  float g3 = *(const float*)(xb + (tw.y >> 16));
  float g4 = *(const float*)(xb + (tw.z & 0xffffu));
  float g5 = *(const float*)(xb + (tw.z >> 16));
  float g6 = *(const float*)(xb + (tw.w & 0xffffu));
  float g7 = *(const float*)(xb + (tw.w >> 16));
  short8 af;
  af[0] = f2bfs(g0); af[1] = f2bfs(g1); af[2] = f2bfs(g2); af[3] = f2bfs(g3);
  af[4] = f2bfs(g4); af[5] = f2bfs(g5); af[6] = f2bfs(g6); af[7] = f2bfs(g7);
  return af;
}

// ---- single-tile MLP: stage1 MFMA (weights from LDS) -> relu -> H LDS -> stage2 MFMA ----
// A-frag: lane holds A[m=l&15][k=(l>>4)*8+j]; C/D: col=l&15, row=(l>>4)*4+reg.
// wf1/wf2 point into LDS (ds_read_b128 per fragment). tab is the only VMEM in the loop.
template <int NKS>
__device__ __forceinline__ void mlp_tile(
    int mt, int lane, const uint4* __restrict__ tab,
    const short8* wf1, const short8* wf2,
    const float (&b1v)[4], const float (&b2v)[2],
    const float* arena, short (*hrow)[72], f32x4 (&a2)[2])
{
  const int cl = lane & 15, qq = lane >> 4;
  const char* xb = (const char*)arena;

  f32x4 acc[4];
#pragma unroll
  for (int nt = 0; nt < 4; ++nt) {
    float bv = b1v[nt];
    acc[nt] = (f32x4){bv, bv, bv, bv};
  }

#pragma unroll
  for (int ks = 0; ks < NKS; ++ks) {
    uint4 tw = tab[(mt * NKS + ks) * 64 + lane];
    short8 af = gather8(xb, tw);
#pragma unroll
    for (int nt = 0; nt < 4; ++nt) {
      short8 wf = wf1[(ks * 4 + nt) * 64 + lane];
      acc[nt] = __builtin_amdgcn_mfma_f32_16x16x32_bf16(af, wf, acc[nt], 0, 0, 0);
    }
  }

  // relu -> per-wave H tile (bf16, rows padded to 72 shorts = 144B, 16B-aligned)
#pragma unroll
  for (int nt = 0; nt < 4; ++nt)
#pragma unroll
    for (int r = 0; r < 4; ++r)
      hrow[qq * 4 + r][nt * 16 + cl] = f2bfs(fmaxf(acc[nt][r], 0.f));

#pragma unroll
  for (int nt = 0; nt < 2; ++nt) {
    float bv = b2v[nt];
    a2[nt] = (f32x4){bv, bv, bv, bv};
  }
#pragma unroll
  for (int k2 = 0; k2 < 2; ++k2) {
    short8 h = *(const short8*)&hrow[cl][k2 * 32 + qq * 8];
#pragma unroll
    for (int nt = 0; nt < 2; ++nt) {
      short8 wf = wf2[(k2 * 2 + nt) * 64 + lane];
      a2[nt] = __builtin_amdgcn_mfma_f32_16x16x32_bf16(h, wf, a2[nt], 0, 0, 0);
    }
  }
}

template <int DIV, int LIM>
__device__ __forceinline__ void scatter_e(const f32x4 (&a2)[2], int rb, float* eb, int cl) {
  int riA = rb / DIV, riB = (rb + 3) / DIV;
#pragma unroll
  for (int nt = 0; nt < 2; ++nt) {
    int col = nt * 16 + cl;
    if (col < 20) {
      if (riA == riB && rb + 3 < LIM) {
        atomicAdd(&eb[riA * 20 + col], a2[nt][0] + a2[nt][1] + a2[nt][2] + a2[nt][3]);
      } else {
#pragma unroll
        for (int r = 0; r < 4; ++r) {
          int rr = rb + r;
          if (rr < LIM) atomicAdd(&eb[(rr / DIV) * 20 + col], a2[nt][r]);
        }
      }
    }
  }
}

// ---------------- fused kernel: one block per batch element ----------------
__global__ __launch_bounds__(256, 3) void fused_kernel(
    const float* __restrict__ x, const float* __restrict__ y,
    const float* __restrict__ Wc, const float* __restrict__ Bc,
    const char* __restrict__ wsb, float* __restrict__ out) {
  __shared__ float arena[ARENA_W];                    // 19724 B
  __shared__ __align__(16) short wlds[20 * 64 * 8];   // 20480 B, reused per branch
  __shared__ short hlds[4][16][72];                   // 9216 B, per-wave H tile
  __shared__ float osum[24];

  const int b = blockIdx.x;
  const int tid = threadIdx.x;
  const int w = tid >> 6;
  const int lane = tid & 63;
  const int cl = lane & 15, q4 = (lane >> 4) * 4;

  // ---- stage inputs + pp weights ----
  for (int k = tid; k < 3600; k += 256) {
    int r = k / 60, c = k - r * 60;
    arena[r * XP + c] = x[(size_t)b * 3600 + k];
  }
  if (tid < 70) arena[Y0 + tid] = y[(size_t)b * 70 + tid];
  for (int k = tid; k < 1200; k += 256) arena[EB0 + k] = 0.f;
  if (tid == 0) arena[ZSLOT] = 0.f;
  if (tid < 24) osum[tid] = 0.f;
  {
    uint4* d = (uint4*)wlds;
    const uint4* sgl = (const uint4*)(wsb + WPP1_B);   // stage1+stage2 contiguous: 20480 B
    for (int k = tid; k < 1280; k += 256) d[k] = sgl[k];
  }
  __syncthreads();

  const float* biasf = (const float*)(wsb + BIAS_B);

  // ================= particle-particle =================
  {
    const short8* wf1 = (const short8*)wlds;
    const short8* wf2 = (const short8*)wlds + 16 * 64;
    const uint4* tab = (const uint4*)(wsb + TABPP_B);
    float b1v[4], b2v[2];
#pragma unroll
    for (int nt = 0; nt < 4; ++nt) b1v[nt] = biasf[0 + nt * 16 + cl];
#pragma unroll
    for (int nt = 0; nt < 2; ++nt) b2v[nt] = biasf[64 + nt * 16 + cl];

    for (int mt = w; mt < 222; mt += 4) {
      f32x4 a2[2];
      mlp_tile<4>(mt, lane, tab, wf1, wf2, b1v, b2v, arena, hlds[w], a2);
      scatter_e<59, 3540>(a2, mt * 16 + q4, &arena[EB0], cl);
    }
  }

  __syncthreads();  // all waves done reading pp weights
  {
    uint4* d = (uint4*)wlds;
    const uint4* sgl = (const uint4*)(wsb + WPV1_B);   // 16384 B
    for (int k = tid; k < 1024; k += 256) d[k] = sgl[k];
  }
  __syncthreads();

  // ================= particle-vertex =================
  {
    const short8* wf1 = (const short8*)wlds;
    const short8* wf2 = (const short8*)wlds + 12 * 64;
    const uint4* tab = (const uint4*)(wsb + TABPV_B);
    float b1v[4], b2v[2];
#pragma unroll
    for (int nt = 0; nt < 4; ++nt) b1v[nt] = biasf[96 + nt * 16 + cl];
#pragma unroll
    for (int nt = 0; nt < 2; ++nt) b2v[nt] = biasf[160 + nt * 16 + cl];

    for (int mt = w; mt < 53; mt += 4) {
      f32x4 a2[2];
      mlp_tile<3>(mt, lane, tab, wf1, wf2, b1v, b2v, arena, hlds[w], a2);
      scatter_e<14, 840>(a2, mt * 16 + q4, &arena[EB0], cl);
    }
  }

  __syncthreads();  // ebar complete + pv weight reads done
  {
    uint4* d = (uint4*)wlds;
    const uint4* sgl = (const uint4*)(wsb + WO1_B);    // 16384 B
    for (int k = tid; k < 1024; k += 256) d[k] = sgl[k];
  }
  __syncthreads();

  // ================= output MLP (4 tiles, one per wave) =================
  {
    const short8* wf1 = (const short8*)wlds;
    const short8* wf2 = (const short8*)wlds + 12 * 64;
    const uint4* tab = (const uint4*)(wsb + TABO_B);
    float b1v[4], b2v[2];
#pragma unroll
    for (int nt = 0; nt < 4; ++nt) b1v[nt] = biasf[192 + nt * 16 + cl];
#pragma unroll
    for (int nt = 0; nt < 2; ++nt) b2v[nt] = biasf[256 + nt * 16 + cl];

    f32x4 a2[2];
    mlp_tile<3>(w, lane, tab, wf1, wf2, b1v, b2v, arena, hlds[w], a2);
    int rb = w * 16 + q4;
#pragma unroll
    for (int nt = 0; nt < 2; ++nt) {
      int col = nt * 16 + cl;
      if (col < 24) {
        if (rb + 3 < 60) {
          atomicAdd(&osum[col], a2[nt][0] + a2[nt][1] + a2[nt][2] + a2[nt][3]);
        } else {
#pragma unroll
          for (int r = 0; r < 4; ++r)
            if (rb + r < 60) atomicAdd(&osum[col], a2[nt][r]);
        }
      }
    }
  }

  __syncthreads();
  if (tid == 0) {
    float sd = Bc[0];
#pragma unroll
    for (int o = 0; o < 24; ++o) sd = fmaf(osum[o], Wc[o], sd);
    out[b] = 1.f / (1.f + expf(-sd));
  }
}

extern "C" void kernel_launch(void* const* d_in, const int* in_sizes, int n_in,
                              void* d_out, int out_size, void* d_ws, size_t ws_size,
                              hipStream_t stream) {
  const float* x     = (const float*)d_in[0];
  const float* y     = (const float*)d_in[1];
  const float* W1_pp = (const float*)d_in[2];
  const float* b1_pp = (const float*)d_in[3];
  const float* W2_pp = (const float*)d_in[4];
  const float* b2_pp = (const float*)d_in[5];
  const float* W1_pv = (const float*)d_in[6];
  const float* b1_pv = (const float*)d_in[7];
  const float* W2_pv = (const float*)d_in[8];
  const float* b2_pv = (const float*)d_in[9];
  const float* W1_o  = (const float*)d_in[10];
  const float* b1_o  = (const float*)d_in[11];
  const float* W2_o  = (const float*)d_in[12];
  const float* b2_o  = (const float*)d_in[13];
  const float* Wc    = (const float*)d_in[14];
  const float* bc    = (const float*)d_in[15];
  float* out = (float*)d_out;
  char* wsb = (char*)d_ws;

  const int Bb = in_sizes[0] / 3600;  // 1024
  const int tab_total = NTAB_PP + NTAB_PV + NTAB_O;

  build_tables<<<(tab_total + 255) / 256, 256, 0, stream>>>(wsb);
  build_wfrag<<<(13600 + 255) / 256, 256, 0, stream>>>(wsb,
      W1_pp, W2_pp, W1_pv, W2_pv, W1_o, W2_o,
      b1_pp, b2_pp, b1_pv, b2_pv, b1_o, b2_o);
  fused_kernel<<<Bb, 256, 0, stream>>>(x, y, Wc, bc, wsb, out);
}